// Round 9
// baseline (936.710 us; speedup 1.0000x reference)
//
#include <hip/hip_runtime.h>
#include <math.h>

#define PIX   16384       // H*W
#define NB    8
#define CIN   256

typedef __attribute__((ext_vector_type(8))) short    short8;   // bf16x8 frag (4 VGPR)
typedef __attribute__((ext_vector_type(4))) float    f32x4;
typedef __attribute__((ext_vector_type(4))) unsigned short us4;
typedef __attribute__((ext_vector_type(8))) unsigned short us8;
typedef __attribute__((ext_vector_type(4))) unsigned char uc4;

__device__ __forceinline__ float bf2f(unsigned short h) {
  return __uint_as_float(((unsigned int)h) << 16);
}
__device__ __forceinline__ unsigned short f2bf(float f) {  // round-nearest-even
  unsigned int u = __float_as_uint(f);
  return (unsigned short)((u + 0x7FFFu + ((u >> 16) & 1u)) >> 16);
}
__device__ __forceinline__ float gelu_f(float v) {
  return 0.5f * v * (1.f + erff(v * 0.70710678118654752f));
}

// order-preserving f32 -> u32 map (unsigned compare == float compare)
__device__ __forceinline__ unsigned fmono(float f) {
  const unsigned u = __float_as_uint(f);
  return (u & 0x80000000u) ? ~u : (u | 0x80000000u);
}

// max/min over the 16 lanes of each DPP row — pure VALU rotate-reduce
__device__ __forceinline__ unsigned umax16(unsigned v) {
  unsigned t;
  t = (unsigned)__builtin_amdgcn_update_dpp((int)v, (int)v, 0x121, 0xF, 0xF, false); v = v > t ? v : t;
  t = (unsigned)__builtin_amdgcn_update_dpp((int)v, (int)v, 0x122, 0xF, 0xF, false); v = v > t ? v : t;
  t = (unsigned)__builtin_amdgcn_update_dpp((int)v, (int)v, 0x124, 0xF, 0xF, false); v = v > t ? v : t;
  t = (unsigned)__builtin_amdgcn_update_dpp((int)v, (int)v, 0x128, 0xF, 0xF, false); v = v > t ? v : t;
  return v;
}
__device__ __forceinline__ int imin16(int v) {
  int t;
  t = __builtin_amdgcn_update_dpp(v, v, 0x121, 0xF, 0xF, false); v = v < t ? v : t;
  t = __builtin_amdgcn_update_dpp(v, v, 0x122, 0xF, 0xF, false); v = v < t ? v : t;
  t = __builtin_amdgcn_update_dpp(v, v, 0x124, 0xF, 0xF, false); v = v < t ? v : t;
  t = __builtin_amdgcn_update_dpp(v, v, 0x128, 0xF, 0xF, false); v = v < t ? v : t;
  return v;
}

// ---------------------------------------------------------------- zero
__global__ void zero_kernel(float* p, int n) {
  int i = blockIdx.x * blockDim.x + threadIdx.x;
  if (i < n) p[i] = 0.f;
}

// ---------------------------------------------------- weight prep (bf16)
// Also emits pwF: proj weights pre-packed in MFMA B-frag order
// pwF[f][ct][ks][lane][j]  (ch = f*64+ct*16+(lane&15), k = ks*32+(lane>>4)*8+j)
__global__ void prep_weights(const float* __restrict__ pw_f, const float* __restrict__ mw_f,
                             const float* __restrict__ w0, const float* __restrict__ w1,
                             unsigned short* __restrict__ pw, unsigned short* __restrict__ mw,
                             unsigned short* __restrict__ w0t, unsigned short* __restrict__ w1t,
                             unsigned short* __restrict__ pwF) {
  const int S1 = 512 * 256, S2 = 256 * 256, S3 = 512 * 512, S4 = 256 * 512, S5 = 512 * 256;
  int i = blockIdx.x * 256 + threadIdx.x;
  if (i < S1) { pw[i] = f2bf(pw_f[i]); return; }
  i -= S1;
  if (i < S2) { mw[i] = f2bf(mw_f[i]); return; }
  i -= S2;
  if (i < S3) { int o = i >> 9, k = i & 511; w0t[i] = f2bf(w0[k * 512 + o]); return; }
  i -= S3;
  if (i < S4) { int o = i >> 9, k = i & 511; w1t[i] = f2bf(w1[k * 256 + o]); return; }
  i -= S4;
  if (i < S5) {
    const int j = i & 7, lane = (i >> 3) & 63, ks = (i >> 9) & 7, ct = (i >> 12) & 3, f = i >> 14;
    const int ch = f * 64 + ct * 16 + (lane & 15);
    const int k  = ks * 32 + (lane >> 4) * 8 + j;
    pwF[i] = f2bf(pw_f[ch * 256 + k]);
  }
}

// ------------------------------------------- x: NCHW fp32 -> NHWC bf16
__global__ __launch_bounds__(256) void x_to_nhwc(const float* __restrict__ x,
                                                 unsigned short* __restrict__ xT) {
  __shared__ float tile[64][65];
  const int t = threadIdx.x;
  const int p0 = blockIdx.x * 64, c0 = blockIdx.y * 64, n = blockIdx.z;
#pragma unroll
  for (int i = 0; i < 4; i++) {
    const int c = i * 16 + (t >> 4);
    const float4 v = *(const float4*)(x + ((size_t)(n * 256 + c0 + c) << 14) + p0 + (t & 15) * 4);
    tile[c][(t & 15) * 4]     = v.x;
    tile[c][(t & 15) * 4 + 1] = v.y;
    tile[c][(t & 15) * 4 + 2] = v.z;
    tile[c][(t & 15) * 4 + 3] = v.w;
  }
  __syncthreads();
#pragma unroll
  for (int i = 0; i < 4; i++) {
    const int pp = i * 16 + (t >> 4);
    const int cl = (t & 15) * 4;
    us4 o;
    o.x = f2bf(tile[cl][pp]); o.y = f2bf(tile[cl + 1][pp]);
    o.z = f2bf(tile[cl + 2][pp]); o.w = f2bf(tile[cl + 3][pp]);
    *(us4*)&xT[(((size_t)n << 14) + p0 + pp) * 256 + c0 + cl] = o;
  }
}

// ---------------------------------------------------------- MFMA GEMM (v1, LDS)
template<bool CONCAT, bool GELU, bool STATS>
__global__ __launch_bounds__(256, 4) void mfma_gemm(
    const unsigned short* __restrict__ A, const float* __restrict__ bias,
    const unsigned short* __restrict__ B1, const unsigned short* __restrict__ B2,
    unsigned short* __restrict__ Y, int M, int K, int K1,
    int astride, int bstride, float* __restrict__ sums) {
  __shared__ unsigned short As[8192];
  __shared__ unsigned short Bs[8192];
  __shared__ float r1[4], r2[4];
  const int t = threadIdx.x;
  const int lane = t & 63, w = t >> 6;
  const int quad = lane >> 4, l16 = lane & 15;
  const int p0 = blockIdx.x * 128, m0 = blockIdx.y * 128;
  const int n = blockIdx.z;
  const int wm = w & 1, wn = w >> 1;
  const int K2 = K - K1;

  A += (size_t)n * astride;

  f32x4 acc[4][4];
#pragma unroll
  for (int im = 0; im < 4; im++)
#pragma unroll
    for (int in = 0; in < 4; in++) acc[im][in] = (f32x4)0.f;

  for (int k0 = 0; k0 < K; k0 += 64) {
    __syncthreads();
#pragma unroll
    for (int i = 0; i < 4; i++) {
      const int c = (w << 2) | i;
      const int tm = c >> 1, kk = c & 1;
      const int krow = k0 + kk * 32 + quad * 8;
      const unsigned short* ga = A + (size_t)(m0 + tm * 16 + l16) * K + krow;
      __builtin_amdgcn_global_load_lds((const __attribute__((address_space(1))) void*)ga,
          (__attribute__((address_space(3))) void*)&As[c * 512], 16, 0, 0);
      const int prow = p0 + tm * 16 + l16;
      const unsigned short* gb;
      if (!CONCAT || krow < K1)
        gb = B1 + ((((size_t)n << 14) + prow) * (size_t)K1) + krow;
      else
        gb = B2 + ((((size_t)n << 14) + prow) * (size_t)K2) + (krow - K1);
      __builtin_amdgcn_global_load_lds((const __attribute__((address_space(1))) void*)gb,
          (__attribute__((address_space(3))) void*)&Bs[c * 512], 16, 0, 0);
    }
    __syncthreads();
#pragma unroll
    for (int kk = 0; kk < 2; kk++) {
      short8 af[4], bfr[4];
#pragma unroll
      for (int im = 0; im < 4; im++)
        af[im] = *(const short8*)&As[(((wm * 4 + im) * 2 + kk) * 64 + lane) * 8];
#pragma unroll
      for (int in = 0; in < 4; in++)
        bfr[in] = *(const short8*)&Bs[(((wn * 4 + in) * 2 + kk) * 64 + lane) * 8];
#pragma unroll
      for (int im = 0; im < 4; im++)
#pragma unroll
        for (int in = 0; in < 4; in++)
          acc[im][in] = __builtin_amdgcn_mfma_f32_16x16x32_bf16(af[im], bfr[in], acc[im][in], 0, 0, 0);
    }
  }

  const size_t nb = ((size_t)n << 14);
  float s = 0.f, s2 = 0.f;
#pragma unroll
  for (int im = 0; im < 4; im++) {
    const int om = m0 + (wm * 4 + im) * 16 + quad * 4;
    const f32x4 bv = *(const f32x4*)(bias + (size_t)n * bstride + om);
#pragma unroll
    for (int in = 0; in < 4; in++) {
      const int p = p0 + (wn * 4 + in) * 16 + l16;
      float v0 = acc[im][in].x + bv.x;
      float v1 = acc[im][in].y + bv.y;
      float v2 = acc[im][in].z + bv.z;
      float v3 = acc[im][in].w + bv.w;
      if (GELU) { v0 = gelu_f(v0); v1 = gelu_f(v1); v2 = gelu_f(v2); v3 = gelu_f(v3); }
      if (STATS) {
        s += (v0 + v1) + (v2 + v3);
        s2 = fmaf(v0, v0, s2); s2 = fmaf(v1, v1, s2);
        s2 = fmaf(v2, v2, s2); s2 = fmaf(v3, v3, s2);
      }
      us4 o4;
      o4.x = f2bf(v0); o4.y = f2bf(v1); o4.z = f2bf(v2); o4.w = f2bf(v3);
      *(us4*)&Y[(nb + p) * M + om] = o4;
    }
  }
  if (STATS) {
#pragma unroll
    for (int off = 32; off > 0; off >>= 1) {
      s += __shfl_down(s, off);
      s2 += __shfl_down(s2, off);
    }
    if (lane == 0) { r1[w] = s; r2[w] = s2; }
    __syncthreads();
    if (t == 0) {
      atomicAdd(&sums[2 * n],     (r1[0] + r1[1]) + (r1[2] + r1[3]));
      atomicAdd(&sums[2 * n + 1], (r2[0] + r2[1]) + (r2[2] + r2[3]));
    }
  }
}

// ============================================================= CLUSTER
// proj is FUSED: center means via linearity (proj(mean xT)), assign computes
// its own 64 y-channels on the fly (bitwise-identical MFMA order to old proj).
// m = 0..255 encodes n(3b) f(3b) s1 s2; region r = (n<<2)|(s1<<1)|s2.

// ---- A0: xT block means. grid (kslice4, region32), block 256.
// thread: b = t>>2 (8x8 block), kq = t&3 (16 k each)
__global__ __launch_bounds__(256) void xmeans_kernel(
    const unsigned short* __restrict__ xT, float* __restrict__ xmean) {
  const int reg = blockIdx.y, ksl = blockIdx.x;
  const int nn = reg >> 2, s1 = (reg >> 1) & 1, s2 = reg & 1;
  const int t = threadIdx.x;
  const int b = t >> 2, kq = t & 3;
  const int k0 = ksl * 64 + kq * 16;
  const size_t nbase = ((size_t)nn << 14);
  const int pr0 = s1 * 64 + (b >> 3) * 8, pc0 = s2 * 64 + (b & 7) * 8;
  float a16[16];
#pragma unroll
  for (int j = 0; j < 16; j++) a16[j] = 0.f;
#pragma unroll 1
  for (int r = 0; r < 8; r++) {
#pragma unroll
    for (int c = 0; c < 8; c++) {
      const unsigned short* xp = xT + (nbase + (size_t)(pr0 + r) * 128 + pc0 + c) * 256 + k0;
      const us8 v0 = *(const us8*)xp;
      const us8 v1 = *(const us8*)(xp + 8);
#pragma unroll
      for (int j = 0; j < 8; j++) {
        a16[j]     += bf2f(v0[j]);
        a16[8 + j] += bf2f(v1[j]);
      }
    }
  }
  float* o = xmean + (((size_t)(reg * 64 + b)) << 8) + k0;
#pragma unroll
  for (int j = 0; j < 16; j++) o[j] = a16[j] * (1.f / 64.f);
}

// ---- A1: per-m center projection (64 b x 64 ch x 256 k, VALU) -> cpnh_g/cval_g.
// grid (m256), block 256; thread (b = t>>2, cg = t&3 -> 16 ch each).
__global__ __launch_bounds__(256) void centers_kernel(
    const float* __restrict__ xmean, const unsigned short* __restrict__ pw,
    const float* __restrict__ proj_bp, unsigned short* __restrict__ cpnh_g,
    float* __restrict__ cval_g) {
  const int m = blockIdx.x;
  const int nn = m >> 5, f = (m >> 2) & 7, s1 = (m >> 1) & 1, s2 = m & 1;
  const int reg = (nn << 2) | (s1 << 1) | s2;
  const int t = threadIdx.x;
  const int b = t >> 2, cg = t & 3;
  __shared__ float cs[64][68];

  {
    const float* xm = xmean + (((size_t)(reg * 64 + b)) << 8);
    float acc16[16];
#pragma unroll
    for (int c = 0; c < 16; c++) acc16[c] = 0.f;
#pragma unroll 1
    for (int k = 0; k < 256; k += 8) {
      float xv[8];
#pragma unroll
      for (int j = 0; j < 8; j++) xv[j] = xm[k + j];
#pragma unroll
      for (int c = 0; c < 16; c++) {
        const us8 wv = *(const us8*)(pw + (size_t)(f * 64 + cg * 16 + c) * 256 + k);
#pragma unroll
        for (int j = 0; j < 8; j++) acc16[c] = fmaf(bf2f(wv[j]), xv[j], acc16[c]);
      }
    }
#pragma unroll
    for (int c = 0; c < 16; c++)
      cs[b][cg * 16 + c] = acc16[c] + proj_bp[f * 64 + cg * 16 + c];
  }
  __syncthreads();

  {
    const int b2 = t >> 2, jg = t & 3;   // 8 ch each
    const f32x4 ov0 = *(const f32x4*)&cs[b2][32 + jg * 8];
    const f32x4 ov1 = *(const f32x4*)&cs[b2][32 + jg * 8 + 4];
    *(f32x4*)&cval_g[(((size_t)(m * 64 + b2)) << 5) + jg * 8]     = ov0;
    *(f32x4*)&cval_g[(((size_t)(m * 64 + b2)) << 5) + jg * 8 + 4] = ov1;
    float s = 0.f;
#pragma unroll
    for (int cc = 0; cc < 32; cc++) { const float v = cs[b2][cc]; s = fmaf(v, v, s); }
    const float inv = 1.f / fmaxf(sqrtf(s), 1e-12f);
    us4 o0, o1;
    o0.x = f2bf(cs[b2][jg * 8] * inv);     o0.y = f2bf(cs[b2][jg * 8 + 1] * inv);
    o0.z = f2bf(cs[b2][jg * 8 + 2] * inv); o0.w = f2bf(cs[b2][jg * 8 + 3] * inv);
    o1.x = f2bf(cs[b2][jg * 8 + 4] * inv); o1.y = f2bf(cs[b2][jg * 8 + 5] * inv);
    o1.z = f2bf(cs[b2][jg * 8 + 6] * inv); o1.w = f2bf(cs[b2][jg * 8 + 7] * inv);
    *(us4*)&cpnh_g[(((size_t)(m * 64 + b2)) << 5) + jg * 8]     = o0;
    *(us4*)&cpnh_g[(((size_t)(m * 64 + b2)) << 5) + jg * 8 + 4] = o1;
  }
}

// ---- B: fused proj + assignment + partial reduction.
// grid (slice16, m256), block 256 (4 waves x 64 pts = 256 points).
// Phase P: y[256 pts][64 ch] = xT @ pwF^T + b, written to frag-packed LDS
//          (bitwise-identical to the old proj GEMM's y values).
// Phase S: MFMA sim + VALU argmax + sigmoid (reads LDS frags).
// Phase R: atomic-free conditional scan -> per-slice partials.
__global__ __launch_bounds__(256, 3) void assign_kernel(
    const unsigned short* __restrict__ xT, const unsigned short* __restrict__ pwF,
    const float* __restrict__ proj_bp, const unsigned short* __restrict__ cpnh_g,
    const float* __restrict__ alpha_p, const float* __restrict__ beta_p,
    float* __restrict__ svals_g, unsigned char* __restrict__ sbest_g,
    float* __restrict__ accp_v, float* __restrict__ accp_c) {
  const int m = blockIdx.y, slice = blockIdx.x;
  const int n = m >> 5, f = (m >> 2) & 7, s1 = (m >> 1) & 1, s2 = m & 1;
  const int t = threadIdx.x;
  const int wave = t >> 6, lane = t & 63;
  const int quad = lane >> 4, l16 = lane & 15;
  const float alpha = alpha_p[0], beta = beta_p[0];

  __shared__ unsigned short ytile[16][2][64][8];  // 32KB frag-packed y
  __shared__ float svalss[256];
  __shared__ unsigned char sidxs[256];

  const size_t nbase = ((size_t)n << 14);
  const int prow0 = s1 * 64, pcol0 = s2 * 64;

  const short8 cb0 = *(const short8*)&cpnh_g[((size_t)(m * 64 +  0 + l16) << 5) + quad * 8];
  const short8 cb1 = *(const short8*)&cpnh_g[((size_t)(m * 64 + 16 + l16) << 5) + quad * 8];
  const short8 cb2 = *(const short8*)&cpnh_g[((size_t)(m * 64 + 32 + l16) << 5) + quad * 8];
  const short8 cb3 = *(const short8*)&cpnh_g[((size_t)(m * 64 + 48 + l16) << 5) + quad * 8];
  const int sl4 = (((l16 >> 2) << 4) | (l16 & 3)) << 2;  // bpermute src addr

  float pb[4];
#pragma unroll
  for (int ct = 0; ct < 4; ct++) pb[ct] = proj_bp[f * 64 + ct * 16 + l16];

  // ---- phase P: proj MFMA for this wave's 64 points
  {
    f32x4 acc[4][4];
#pragma unroll
    for (int pt = 0; pt < 4; pt++)
#pragma unroll
      for (int ct = 0; ct < 4; ct++) acc[pt][ct] = (f32x4)0.f;
    const unsigned short* pwb = pwF + ((size_t)f << 14);   // f*4*8*64*8
#pragma unroll 1
    for (int ks = 0; ks < 8; ks++) {
      short8 af[4], bf_[4];
#pragma unroll
      for (int pt = 0; pt < 4; pt++) {
        const int pidx = slice * 256 + wave * 64 + pt * 16;
        const int pix = (prow0 + (pidx >> 6)) * 128 + pcol0 + (pidx & 63) + l16;
        af[pt] = *(const short8*)(xT + (nbase + pix) * (size_t)256 + ks * 32 + quad * 8);
      }
#pragma unroll
      for (int ct = 0; ct < 4; ct++)
        bf_[ct] = *(const short8*)(pwb + ((ct * 8 + ks) * 64 + lane) * 8);
#pragma unroll
      for (int pt = 0; pt < 4; pt++)
#pragma unroll
        for (int ct = 0; ct < 4; ct++)
          acc[pt][ct] = __builtin_amdgcn_mfma_f32_16x16x32_bf16(af[pt], bf_[ct], acc[pt][ct], 0, 0, 0);
    }
    // epilogue: bias + bf16 -> frag-packed LDS
#pragma unroll
    for (int pt = 0; pt < 4; pt++) {
      const int tileG = wave * 4 + pt;
#pragma unroll
      for (int ct = 0; ct < 4; ct++) {
        const int ch = ct * 16 + l16;
        const int half = ch >> 5, chm = ch & 31;
        const int dq = chm >> 3, j = chm & 7;
#pragma unroll
        for (int r = 0; r < 4; r++) {
          const float v = acc[pt][ct][r] + pb[ct];
          ytile[tileG][half][dq * 16 + (quad * 4 + r)][j] = f2bf(v);
        }
      }
    }
  }
  __syncthreads();

  // ---- phase S: sim + argmax + sigmoid, tiles wave*4 .. +3
#pragma unroll 1
  for (int tt = 0; tt < 4; tt++) {
    const int tile = wave * 4 + tt;
    const short8 apt = *(const short8*)&ytile[tile][0][quad * 16 + l16][0];
    const short8 avl = *(const short8*)&ytile[tile][1][quad * 16 + l16][0];
    (void)avl;

    float nrm = 0.f;
#pragma unroll
    for (int j = 0; j < 8; j++) {
      const float fv = bf2f((unsigned short)apt[j]);
      nrm = fmaf(fv, fv, nrm);
    }
    nrm += __shfl_xor(nrm, 16);
    nrm += __shfl_xor(nrm, 32);
    const float inva = 1.f / fmaxf(sqrtf(nrm), 1e-12f);

    const f32x4 d0 = __builtin_amdgcn_mfma_f32_16x16x32_bf16(apt, cb0, (f32x4)0.f, 0, 0, 0);
    const f32x4 d1 = __builtin_amdgcn_mfma_f32_16x16x32_bf16(apt, cb1, (f32x4)0.f, 0, 0, 0);
    const f32x4 d2 = __builtin_amdgcn_mfma_f32_16x16x32_bf16(apt, cb2, (f32x4)0.f, 0, 0, 0);
    const f32x4 d3 = __builtin_amdgcn_mfma_f32_16x16x32_bf16(apt, cb3, (f32x4)0.f, 0, 0, 0);

    float bv[4]; int bi[4];
#pragma unroll
    for (int r = 0; r < 4; r++) {
      const unsigned u0 = fmono(d0[r]);
      const unsigned u1 = fmono(d1[r]);
      const unsigned u2 = fmono(d2[r]);
      const unsigned u3 = fmono(d3[r]);
      unsigned mx = u0 > u1 ? u0 : u1;
      const unsigned mxb = u2 > u3 ? u2 : u3;
      mx = mx > mxb ? mx : mxb;
      mx = umax16(mx);
      int c0 = (u0 == mx) ? l16        : 64;
      int c1 = (u1 == mx) ? (16 + l16) : 64;
      int c2 = (u2 == mx) ? (32 + l16) : 64;
      int c3 = (u3 == mx) ? (48 + l16) : 64;
      int ci = c0 < c1 ? c0 : c1;
      const int cb = c2 < c3 ? c2 : c3;
      ci = ci < cb ? ci : cb;
      ci = imin16(ci);
      bi[r] = ci;
      bv[r] = __uint_as_float((mx & 0x80000000u) ? (mx ^ 0x80000000u) : ~mx);
    }

    const float rv01 = (l16 & 1) ? bv[1] : bv[0];
    const float rv23 = (l16 & 1) ? bv[3] : bv[2];
    const float rowv = (l16 & 2) ? rv23 : rv01;
    const int   ri01 = (l16 & 1) ? bi[1] : bi[0];
    const int   ri23 = (l16 & 1) ? bi[3] : bi[2];
    const int   rowi = (l16 & 2) ? ri23 : ri01;
    const unsigned pk = (__float_as_uint(rowv) & ~63u) | (unsigned)rowi;
    const unsigned got = (unsigned)__builtin_amdgcn_ds_bpermute(sl4, (int)pk);
    const int   idx = (int)(got & 63u);
    const float dot = __uint_as_float(got & ~63u);

    const float val = 1.f / (1.f + __expf(-fmaf(alpha, dot * inva, beta)));
    if (quad == 0) {
      const int pidxg = slice * 256 + tile * 16 + l16;
      svals_g[(size_t)m * 4096 + pidxg] = val;
      sbest_g[(size_t)m * 4096 + pidxg] = (unsigned char)idx;
      svalss[tile * 16 + l16] = val;
      sidxs[tile * 16 + l16] = (unsigned char)idx;
    }
  }
  __syncthreads();

  // ---- phase R: atomic-free reduction. thread (b=t>>2, g=t&3)
  {
    const int b = t >> 2, g = t & 3;
    float a8[8] = {0.f, 0.f, 0.f, 0.f, 0.f, 0.f, 0.f, 0.f};
    float ac = 0.f;
#pragma unroll 4
    for (int p4 = 0; p4 < 64; p4++) {
      const uc4 i4 = *(const uc4*)&sidxs[p4 * 4];
#pragma unroll
      for (int u = 0; u < 4; u++) {
        const int idx = (u == 0) ? i4.x : (u == 1) ? i4.y : (u == 2) ? i4.z : i4.w;
        if (idx == b) {
          const int p = p4 * 4 + u;
          const float val = svalss[p];
          const us8 yv = *(const us8*)&ytile[p >> 4][1][(g << 4) | (p & 15)][0];
#pragma unroll
          for (int j = 0; j < 8; j++) a8[j] = fmaf(val, bf2f(yv[j]), a8[j]);
          ac += val;
        }
      }
    }
    const size_t pbx = ((size_t)(m * 16 + slice)) * 64;
    f32x4 o0, o1;
    o0.x = a8[0]; o0.y = a8[1]; o0.z = a8[2]; o0.w = a8[3];
    o1.x = a8[4]; o1.y = a8[5]; o1.z = a8[6]; o1.w = a8[7];
    *(f32x4*)&accp_v[(pbx + b) * 32 + g * 8]     = o0;
    *(f32x4*)&accp_v[(pbx + b) * 32 + g * 8 + 4] = o1;
    if (g == 0) accp_c[pbx + b] = ac;
  }
}

// ---- D: reduce partial means + gather -> nx. grid (slice8, m256), block 256.
__global__ __launch_bounds__(256) void gather_kernel(
    const float* __restrict__ accp_v, const float* __restrict__ accp_c,
    const float* __restrict__ cval_g, const float* __restrict__ svals_g,
    const unsigned char* __restrict__ sbest_g, unsigned short* __restrict__ nx) {
  const int m = blockIdx.y, slice = blockIdx.x;
  const int n = m >> 5, f = (m >> 2) & 7, s1 = (m >> 1) & 1, s2 = m & 1;
  const int t = threadIdx.x;
  __shared__ float cm[64][34];

  const size_t nbase = ((size_t)n << 14);
  const int prow0 = s1 * 64, pcol0 = s2 * 64;

  for (int i = t; i < 2048; i += 256) {
    const int b = i >> 5, q = i & 31;
    float s = cval_g[((size_t)(m * 64 + b) << 5) + q];
    float c = 1.f;
#pragma unroll
    for (int s16 = 0; s16 < 16; s16++) {
      const size_t pbx = ((size_t)(m * 16 + s16)) * 64 + b;
      s += accp_v[pbx * 32 + q];
      c += accp_c[pbx];
    }
    cm[b][q] = s / c;
  }
  __syncthreads();

#pragma unroll
  for (int pass = 0; pass < 2; pass++) {
    const int l = slice * 512 + pass * 256 + t;
    const int p = (prow0 + (l >> 6)) * 128 + pcol0 + (l & 63);
    const float v = svals_g[(size_t)m * 4096 + l];
    const int b = sbest_g[(size_t)m * 4096 + l];
    unsigned short* nr = nx + (nbase + p) * 256 + f * 32;
#pragma unroll
    for (int q8 = 0; q8 < 4; q8++) {
      const float2 a0 = *(const float2*)&cm[b][q8 * 8];
      const float2 a1 = *(const float2*)&cm[b][q8 * 8 + 2];
      const float2 a2 = *(const float2*)&cm[b][q8 * 8 + 4];
      const float2 a3 = *(const float2*)&cm[b][q8 * 8 + 6];
      us8 o;
      o[0] = f2bf(v * a0.x); o[1] = f2bf(v * a0.y);
      o[2] = f2bf(v * a1.x); o[3] = f2bf(v * a1.y);
      o[4] = f2bf(v * a2.x); o[5] = f2bf(v * a2.y);
      o[6] = f2bf(v * a3.x); o[7] = f2bf(v * a3.y);
      *(us8*)&nr[q8 * 8] = o;
    }
  }
}

// ---------------- GN0 per-(n,c) affine coefficients from fused sums
__global__ void gn_finalize0(const float* __restrict__ sums, const float* __restrict__ g0w,
                             const float* __restrict__ g0b, float* __restrict__ scl,
                             float* __restrict__ bia) {
  const int n = blockIdx.x, c = threadIdx.x;
  const float cntinv = 1.f / (float)(CIN * PIX);
  const float mu = sums[2 * n] * cntinv;
  const float var = sums[2 * n + 1] * cntinv - mu * mu;
  const float rs = rsqrtf(var + 1e-5f);
  const float a = rs * g0w[c];
  scl[n * 256 + c] = a;
  bia[n * 256 + c] = g0b[c] - mu * a;
}

// ---------------- fold GN0 scale into MLP0 weights (per image)
__global__ void w0_scale(const unsigned short* __restrict__ w0t,
                         const float* __restrict__ scl, unsigned short* __restrict__ w0s) {
  const int n = blockIdx.y;
  const int i = blockIdx.x * 256 + threadIdx.x;   // 0..262143
  const int k = i & 511;
  unsigned short v = w0t[i];
  if (k >= 256) v = f2bf(bf2f(v) * scl[n * 256 + k - 256]);
  w0s[(size_t)n * 262144 + i] = v;
}

// ---------------- effective MLP0 bias: b0e[n][o] = b0[o] + sum_k W0n[o][k]*bia[n][k]
__global__ void b0_eff(const unsigned short* __restrict__ w0t, const float* __restrict__ b0,
                       const float* __restrict__ bia, float* __restrict__ b0e) {
  const int n = blockIdx.y;
  const int o = blockIdx.x * 256 + threadIdx.x;   // 0..511
  float s = b0[o];
  const unsigned short* wr = w0t + (size_t)o * 512 + 256;
  const float* br = bia + n * 256;
#pragma unroll 4
  for (int k = 0; k < 256; k++) s = fmaf(bf2f(wr[k]), br[k], s);
  b0e[n * 512 + o] = s;
}

// ------------------- final: GN1 affine + layer_scale + residual, NHWC->NCHW
__global__ __launch_bounds__(256) void final_transpose(
    const unsigned short* __restrict__ u, const float* __restrict__ x,
    const float* __restrict__ sums, const float* __restrict__ g1w,
    const float* __restrict__ g1b, const float* __restrict__ lsc,
    float* __restrict__ out) {
  __shared__ float tile[64][68];
  const int t = threadIdx.x;
  const int p0 = blockIdx.x * 64, c0 = blockIdx.y * 64, n = blockIdx.z;
  {
    const int pl = t >> 2, g = t & 3;
    const unsigned short* up = u + ((((size_t)n << 14) + p0 + pl) << 8) + c0 + g * 16;
    const us8 v0 = *(const us8*)up;
    const us8 v1 = *(const us8*)(up + 8);
#pragma unroll
    for (int j = 0; j < 8; j++) {
      tile[pl][g * 16 + j] = bf2f(v0[j]);
      tile[pl][g * 16 + 8 + j] = bf2f(v1[j]);
    }
  }
  __syncthreads();
  {
    const int cl = t >> 2, g = t & 3;
    const int c = c0 + cl;
    const float cntinv = 1.f / (float)(CIN * PIX);
    const float mu = sums[2 * n] * cntinv;
    const float var = sums[2 * n + 1] * cntinv - mu * mu;
    const float rs = rsqrtf(var + 1e-5f);
    const float gw = rs * g1w[c] * lsc[c];
    const float gb = (g1b[c] - mu * rs * g1w[c]) * lsc[c];
    const size_t rowb = ((size_t)(n * 256 + c) << 14) + p0 + g * 16;
#pragma unroll
    for (int q = 0; q < 4; q++) {
      const float4 xv = *(const float4*)(x + rowb + q * 4);
      float4 o;
      o.x = fmaf(tile[g * 16 + q * 4][cl], gw, gb) + xv.x;
      o.y = fmaf(tile[g * 16 + q * 4 + 1][cl], gw, gb) + xv.y;
      o.z = fmaf(tile[g * 16 + q * 4 + 2][cl], gw, gb) + xv.z;
      o.w = fmaf(tile[g * 16 + q * 4 + 3][cl], gw, gb) + xv.w;
      *(float4*)(out + rowb + q * 4) = o;
    }
  }
}

// ---------------------------------------------------------------- launch
extern "C" void kernel_launch(void* const* d_in, const int* in_sizes, int n_in,
                              void* d_out, int out_size, void* d_ws, size_t ws_size,
                              hipStream_t stream) {
  const float* x       = (const float*)d_in[0];
  const float* proj_w  = (const float*)d_in[1];
  const float* proj_b  = (const float*)d_in[2];
  const float* merge_w = (const float*)d_in[3];
  const float* merge_b = (const float*)d_in[4];
  const float* alpha   = (const float*)d_in[5];
  const float* beta    = (const float*)d_in[6];
  const float* g0w     = (const float*)d_in[7];
  const float* g0b     = (const float*)d_in[8];
  const float* w0      = (const float*)d_in[9];
  const float* b0      = (const float*)d_in[10];
  const float* w1      = (const float*)d_in[11];
  const float* b1      = (const float*)d_in[12];
  const float* g1w     = (const float*)d_in[13];
  const float* g1b     = (const float*)d_in[14];
  const float* lsc     = (const float*)d_in[15];
  float* out = (float*)d_out;

  // workspace (ushort units); newx + cluster scratch live in d_out
  unsigned short* wsu = (unsigned short*)d_ws;
  unsigned short* xT  = wsu;                      // 8*16384*256
  unsigned short* y   = xT + (size_t)33554432;    // 8*16384*512 (h; xmean reuses head)
  unsigned short* nx  = y + (size_t)67108864;     // 8*16384*256 (reused as u)
  unsigned short* pw  = nx + (size_t)33554432;    // 512*256
  unsigned short* mw  = pw + 131072;              // 256*256
  unsigned short* w0t = mw + 65536;               // 512*512
  unsigned short* w1t = w0t + 262144;             // 256*512
  unsigned short* w0s = w1t + 131072;             // 8*512*512
  float* sums = (float*)(w0s + (size_t)2097152);  // 32
  float* scl0 = sums + 32;                        // 8*256
  float* bia0 = scl0 + 2048;                      // 8*256
  float* b0e  = bia0 + 2048;                      // 8*512
  unsigned short* pwF = (unsigned short*)(b0e + 4096);  // 512*256 frag-packed
  float* xmean = (float*)y;                       // 32*64*256 f32 (dead before MLP0)
  unsigned short* newx = (unsigned short*)d_out;  // scratch inside out (64MB)

  // cluster scratch in the upper part of d_out (dead before final_transpose)
  float* svals_g = (float*)((char*)d_out + 67108864);       // 256*4096 f32 (4MB)
  float* cval_g  = svals_g + 1048576;                       // 256*64*32 f32 (2MB)
  float* accp_v  = cval_g + 524288;                         // 256*16*64*32 f32 (32MB)
  float* accp_c  = accp_v + 8388608;                        // 256*16*64 f32 (1MB)
  unsigned short* cpnh_g = (unsigned short*)(accp_c + 262144);  // 256*64*32 bf16 (1MB)
  unsigned char*  sbest_g = (unsigned char*)(cpnh_g + 524288);  // 256*4096 u8 (1MB)

  zero_kernel<<<1, 64, 0, stream>>>(sums, 32);
  prep_weights<<<2816, 256, 0, stream>>>(proj_w, merge_w, w0, w1, pw, mw, w0t, w1t, pwF);
  x_to_nhwc<<<dim3(256, 4, NB), 256, 0, stream>>>(x, xT);

  // cluster (proj fused)
  xmeans_kernel<<<dim3(4, 32), 256, 0, stream>>>(xT, xmean);
  centers_kernel<<<256, 256, 0, stream>>>(xmean, pw, proj_b, cpnh_g, cval_g);
  assign_kernel<<<dim3(16, 256), 256, 0, stream>>>(
      xT, pwF, proj_b, cpnh_g, alpha, beta, svals_g, sbest_g, accp_v, accp_c);
  gather_kernel<<<dim3(8, 256), 256, 0, stream>>>(
      accp_v, accp_c, cval_g, svals_g, sbest_g, nx);

  // merge: newx = mw @ nx, fused GN0 stats -> sums[0..15]
  mfma_gemm<false, false, true><<<dim3(128, 2, NB), 256, 0, stream>>>(
      mw, merge_b, nx, nullptr, newx, 256, 256, 256, 0, 0, sums);

  // GN0 affine coefficients, folded weights & bias
  gn_finalize0<<<NB, 256, 0, stream>>>(sums, g0w, g0b, scl0, bia0);
  w0_scale<<<dim3(1024, NB), 256, 0, stream>>>(w0t, scl0, w0s);
  b0_eff<<<dim3(2, NB), 256, 0, stream>>>(w0t, b0, bia0, b0e);

  // MLP0: h = gelu(w0s_n @ [xT ; newx] + b0e_n)   (h reuses y)
  mfma_gemm<true, true, false><<<dim3(128, 4, NB), 256, 0, stream>>>(
      w0s, b0e, xT, newx, y, 512, 512, 256, 262144, 512, nullptr);

  // MLP1: u = w1t @ h + b1, fused GN1 stats -> sums[16..31]   (u reuses nx)
  mfma_gemm<false, false, true><<<dim3(128, 2, NB), 256, 0, stream>>>(
      w1t, b1, y, nullptr, nx, 256, 512, 512, 0, 0, sums + 16);

  // final transpose/residual
  final_transpose<<<dim3(256, 4, NB), 256, 0, stream>>>(
      nx, x, sums + 16, g1w, g1b, lsc, out);
}